// Round 15
// baseline (67.155 us; speedup 1.0000x reference)
//
#include <hip/hip_runtime.h>

#define B_N 8
#define A_N 100000
#define M_N 64
#define TPB 256
#define QUADS (A_N / 4)                               // 25000, A_N % 4 == 0
#define GX ((QUADS + TPB - 1) / TPB)                  // 98 blocks per batch

#define NBINS 256
#define BINW  12.0f         // covers a0 in [0, 3072); a0 <= 3000
#define MAXAW 50.0f
#define MARG  1.0f

// d_ws: ws_num[B_N*GX], ws_cnt[B_N*GX]. Each slot written every call before
// rl_final reads it (poison-proof). No prep kernel: blocks build the 2KB bin
// table ann-side (~6 LDS atomicOr per ann on one wave) + 1KB ann cache.
// ANCH=4: 784 blocks total (halved prep duplication + dispatch ramp).

__global__ __launch_bounds__(TPB) void rl_main(
    const float* __restrict__ regressions,   // (B, A, 2)
    const float* __restrict__ anchors,       // (1, A, 2)
    const float* __restrict__ annotations,   // (B, M, 3)
    float* __restrict__ ws_num, float* __restrict__ ws_cnt)
{
    __shared__ unsigned int tblLo[NBINS];       // bits 0..31  (anns 0-31)
    __shared__ unsigned int tblHi[NBINS];       // bits 32..63 (anns 32-63)
    __shared__ float4 annl[M_N];                // {x1, x2, len, 0}
    const int b = blockIdx.y;
    const int tid = threadIdx.x;

    // issue anchor loads FIRST: their HBM latency hides under LDS prep
    const int quad_raw = blockIdx.x * TPB + tid;
    const bool qact = (quad_raw < QUADS);
    const int quad = qact ? quad_raw : (QUADS - 1);
    const float4 ancA = ((const float4*)anchors)[2 * quad];      // anchors 4q,4q+1
    const float4 ancB = ((const float4*)anchors)[2 * quad + 1];  // anchors 4q+2,4q+3

    // ---- in-block prep, ann-side scatter ----
    tblLo[tid] = 0u;
    tblHi[tid] = 0u;
    __syncthreads();
    if (tid < M_N) {
        const float* p = annotations + (b * M_N + tid) * 3;
        float x1 = p[0], x2 = p[1];
        const float lab = p[2];
        const bool valid = (lab != -1.0f);
        if (!valid) { x1 = 1e30f; x2 = 1e30f; }   // never enters the table
        annl[tid] = make_float4(x1, x2, x2 - x1, 0.0f);
        if (valid) {
            // iou>=0.5 => overlap >= len/3 => a0 in [x1+len/3-aw, x2-len/3],
            // aw<=50. Margin 1.0 >> fp32 rounding at coords <= ~3e3.
            // bin k intersects [lo,hi] iff k in [floor(lo/W), floor(hi/W)].
            const float len3 = (x2 - x1) * (1.0f / 3.0f);
            const float lo = x1 + len3 - MAXAW - MARG;
            const float hi = x2 - len3 + MARG;
            const int blo = max(0, (int)floorf(lo * (1.0f / BINW)));
            const int bhi = min(NBINS - 1, (int)floorf(hi * (1.0f / BINW)));
            const unsigned int bit = 1u << (tid & 31);
            unsigned int* dst = (tid < 32) ? tblLo : tblHi;
            for (int bb = blo; bb <= bhi; ++bb) atomicOr(&dst[bb], bit);
        }
    }
    __syncthreads();

    // ---- hot phase: 4 anchors per thread (2 float4s) ----
    float lsum = 0.0f, lpos = 0.0f;
    #pragma unroll
    for (int k = 0; k < 4; ++k) {
        const float4 anc2 = (k < 2) ? ancA : ancB;
        const float a0 = (k & 1) ? anc2.z : anc2.x;
        const float a1 = (k & 1) ? anc2.w : anc2.y;
        const float aw = a1 - a0;
        const int a_idx = 4 * quad + k;

        const int bin = min(max((int)(a0 * (1.0f / BINW)), 0), NBINS - 1);
        unsigned long long mask =
            ((unsigned long long)tblHi[bin] << 32) |
            (unsigned long long)tblLo[bin];

        // exact argmax over the candidate superset, ascending index,
        // strict '>' (division-free cross-mul on iou = iw/(S-iw), S=aw+len)
        float iwb = -1.0f, Sb = 1.0f;    // encodes iou = -1
        float bx1 = 1e30f, blen = 0.0f;  // winner carries its values
        while (mask) {
            const int m = __ffsll(mask) - 1;
            mask &= mask - 1;
            const float4 g = annl[m];
            const float iw = fmaxf(fminf(a1, g.y) - fmaxf(a0, g.x), 0.0f);
            const float S  = aw + g.z;
            if (iw * Sb > iwb * S) { iwb = iw; Sb = S; bx1 = g.x; blen = g.z; }
        }

        // exact gate, reference rounding order: ua = (aw+len) - iw
        const float ua  = fmaxf(Sb - iwb, 1e-8f);
        const float iou = iwb / ua;
        if (qact && iou >= 0.5f) {
            const float gcx = bx1 + 0.5f * blen;
            const float gw  = fmaxf(blen, 1.0f);
            const float acx = a0 + 0.5f * aw;
            const float tdx = ((gcx - acx) / aw) / 0.1f;
            const float tdw = logf(gw / aw) / 0.2f;
            const float2 rg =
                ((const float2*)regressions)[(size_t)b * A_N + a_idx];
            const float d0 = fabsf(tdx - rg.x);
            const float d1 = fabsf(tdw - rg.y);
            const float inv9 = 1.0f / 9.0f;
            const float s0 = (d0 <= inv9) ? 4.5f * d0 * d0 : d0 - 0.5f / 9.0f;
            const float s1 = (d1 <= inv9) ? 4.5f * d1 * d1 : d1 - 0.5f / 9.0f;
            lsum += s0 + s1;
            lpos += 1.0f;
        }
    }

    for (int o = 32; o > 0; o >>= 1) {
        lsum += __shfl_down(lsum, o, 64);
        lpos += __shfl_down(lpos, o, 64);
    }
    __shared__ float wsum[TPB / 64], wpos[TPB / 64];
    const int wid  = tid >> 6;
    const int lane = tid & 63;
    if (lane == 0) { wsum[wid] = lsum; wpos[wid] = lpos; }
    __syncthreads();
    if (tid == 0) {
        float s = 0.0f, p = 0.0f;
        #pragma unroll
        for (int w = 0; w < TPB / 64; ++w) { s += wsum[w]; p += wpos[w]; }
        const int slot = b * GX + blockIdx.x;
        ws_num[slot] = s;
        ws_cnt[slot] = p;
    }
}

__global__ __launch_bounds__(512) void rl_final(
    const float* __restrict__ ws_num,
    const float* __restrict__ ws_cnt,
    float* __restrict__ out)
{
    const int wid  = threadIdx.x >> 6;   // wave w handles batch w
    const int lane = threadIdx.x & 63;
    float s = 0.0f, c = 0.0f;
    for (int i = lane; i < GX; i += 64) {
        s += ws_num[wid * GX + i];
        c += ws_cnt[wid * GX + i];
    }
    for (int o = 32; o > 0; o >>= 1) {
        s += __shfl_down(s, o, 64);
        c += __shfl_down(c, o, 64);
    }
    __shared__ float pb[B_N];
    if (lane == 0) {
        const float cnt = 2.0f * c;
        pb[wid] = (cnt > 0.0f) ? s / fmaxf(cnt, 1.0f) : 0.0f;
    }
    __syncthreads();
    if (threadIdx.x == 0) {
        float acc = 0.0f;
        #pragma unroll
        for (int i = 0; i < B_N; ++i) acc += pb[i];
        out[0] = acc * (1.0f / (float)B_N);
    }
}

extern "C" void kernel_launch(void* const* d_in, const int* in_sizes, int n_in,
                              void* d_out, int out_size, void* d_ws, size_t ws_size,
                              hipStream_t stream) {
    const float* regressions = (const float*)d_in[0];
    const float* anchors     = (const float*)d_in[1];
    const float* annotations = (const float*)d_in[2];
    float* out = (float*)d_out;

    float* ws_num = (float*)d_ws;                 // [B_N * GX]
    float* ws_cnt = ws_num + B_N * GX;            // [B_N * GX]

    rl_main<<<dim3(GX, B_N), TPB, 0, stream>>>(regressions, anchors,
                                               annotations, ws_num, ws_cnt);
    rl_final<<<1, 512, 0, stream>>>(ws_num, ws_cnt, out);
}